// Round 1
// 1178.519 us; speedup vs baseline: 1.1370x; 1.1370x over previous
//
#include <hip/hip_runtime.h>
#include <hip/hip_bf16.h>
#include <stdint.h>

typedef __bf16 bf16;
typedef __bf16 bf16x8 __attribute__((ext_vector_type(8)));
typedef __bf16 bf16x4 __attribute__((ext_vector_type(4)));
typedef float  f32x4  __attribute__((ext_vector_type(4)));

#define MFMA(a,b,c) __builtin_amdgcn_mfma_f32_16x16x32_bf16((a), (b), (c), 0, 0, 0)

static constexpr int V_  = 50257;
static constexpr int C_  = 1024;
static constexpr int H_  = 16;
static constexpr int HD_ = 64;
static constexpr int B_  = 2;
static constexpr int T_  = 1024;
static constexpr int M_  = B_ * T_;          // 2048
static constexpr int NT_ = (V_ + 127) / 128; // 393 n-tiles for LM head

// ---- workspace layout (bytes) ----
static constexpr size_t X_OFF  = 0;                                   // X bf16 [2048][1024]
static constexpr size_t WT_OFF = X_OFF  + (size_t)M_ * C_ * 2;        // Wt bf16 [3*16][64][1024]
static constexpr size_t Q_OFF  = WT_OFF + (size_t)3 * H_ * HD_ * C_ * 2;
static constexpr size_t K_OFF  = Q_OFF  + (size_t)B_ * H_ * T_ * HD_ * 2;
static constexpr size_t VT_OFF = K_OFF  + (size_t)B_ * H_ * T_ * HD_ * 2;
static constexpr size_t X2_OFF = VT_OFF + (size_t)B_ * H_ * T_ * HD_ * 2;

// async global->LDS, 16B per lane; LDS dest is wave-uniform base + lane*16
typedef const unsigned int __attribute__((address_space(1)))* gas1_t;
typedef unsigned int __attribute__((address_space(3)))* las3_t;
__device__ __forceinline__ void async_ld16(const void* g, void* l) {
  __builtin_amdgcn_global_load_lds((gas1_t)g, (las3_t)l, 16, 0, 0);
}

// ---- T2 XOR swizzle for [*][64] bf16 tiles (128 B rows, 8 chunks of 16 B) ----
// LDS position (row, p) holds data chunk p ^ (row&7).  Reads/writes of data
// chunk c for row r go to element index  r*64 + ((c ^ (r&7)) << 3).
// Staged via global_load_lds (linear LDS dest): lane supplies pre-swizzled
// global source chunk ( (ln&7) ^ (ln>>3) ) instead of (ln&7).
__device__ __forceinline__ int swz8(int row, int chunk) {
  return row * 64 + ((chunk ^ (row & 7)) << 3);
}

// ---------------- K0: transpose+convert Wq/Wk/Wv -> Wt[wh][d][c] bf16 ----------------
__global__ __launch_bounds__(256) void k_prep_wt(const float* __restrict__ Wq,
                                                 const float* __restrict__ Wk,
                                                 const float* __restrict__ Wv,
                                                 bf16* __restrict__ Wt) {
  __shared__ bf16 tr[64][65];
  int wh = blockIdx.y;            // w*16 + h
  int c0 = blockIdx.x * 64;
  const float* Wsrc = (wh < 16) ? Wq : (wh < 32) ? Wk : Wv;
  int h = wh & 15;
  #pragma unroll
  for (int i = 0; i < 16; ++i) {
    int lin = i * 256 + threadIdx.x;
    int cl = lin >> 6, dl = lin & 63;
    float val = Wsrc[((size_t)h * C_ + (c0 + cl)) * HD_ + dl];
    tr[dl][cl] = (bf16)val;
  }
  __syncthreads();
  bf16* dst = Wt + (size_t)wh * HD_ * C_;
  #pragma unroll
  for (int i = 0; i < 16; ++i) {
    int lin = i * 256 + threadIdx.x;
    int dl = lin >> 6, cl = lin & 63;
    dst[(size_t)dl * C_ + c0 + cl] = tr[dl][cl];
  }
}

// ---------------- K1: x = tok_emb[idx] + pos_emb -> bf16 ----------------
__global__ __launch_bounds__(256) void k_embed(const int* __restrict__ idx,
                                               const float* __restrict__ tok,
                                               const float* __restrict__ pos,
                                               bf16* __restrict__ X) {
  int bt = blockIdx.x;
  int t  = bt & (T_ - 1);
  int v  = idx[bt];
  int c  = threadIdx.x * 4;
  float4 te = *(const float4*)(tok + (size_t)v * C_ + c);
  float4 pe = *(const float4*)(pos + (size_t)t * C_ + c);
  bf16x4 o;
  o[0] = (bf16)(te.x + pe.x); o[1] = (bf16)(te.y + pe.y);
  o[2] = (bf16)(te.z + pe.z); o[3] = (bf16)(te.w + pe.w);
  *(bf16x4*)(X + (size_t)bt * C_ + c) = o;
}

// ---------------- K2: Q/K/V projections (M=2048, N=64, K=1024 per head) ----------------
__global__ __launch_bounds__(256) void k_qkv(const bf16* __restrict__ X,
                                             const bf16* __restrict__ Wt,
                                             bf16* __restrict__ Q,
                                             bf16* __restrict__ Kk,
                                             bf16* __restrict__ Vt) {
  __shared__ __align__(16) bf16 As[128 * 64];
  __shared__ __align__(16) bf16 Bs[64 * 64];
  int m0 = blockIdx.x * 128;
  int wh = blockIdx.y;
  int w = wh >> 4, h = wh & 15;
  int tid = threadIdx.x, wv = tid >> 6, ln = tid & 63;
  int swsrc = ((ln & 7) ^ (ln >> 3)) * 16;   // pre-swizzled source chunk byte offset
  const bf16* wbase = Wt + (size_t)wh * HD_ * C_;
  f32x4 acc[2][4] = {};
  for (int kt = 0; kt < C_ / 64; ++kt) {
    int k0 = kt * 64;
    #pragma unroll
    for (int i = 0; i < 4; ++i) {
      int r0 = i * 32 + wv * 8, r = r0 + (ln >> 3);
      async_ld16((const char*)(X + (size_t)(m0 + r) * C_ + k0) + swsrc, &As[r0 * 64]);
    }
    #pragma unroll
    for (int i = 0; i < 2; ++i) {
      int r0 = i * 32 + wv * 8, r = r0 + (ln >> 3);
      async_ld16((const char*)(wbase + (size_t)r * C_ + k0) + swsrc, &Bs[r0 * 64]);
    }
    __syncthreads();
    #pragma unroll
    for (int ks = 0; ks < 2; ++ks) {
      bf16x8 a[2], b[4];
      #pragma unroll
      for (int mi = 0; mi < 2; ++mi)
        a[mi] = *(const bf16x8*)&As[swz8(wv * 32 + mi * 16 + (ln & 15), ks * 4 + (ln >> 4))];
      #pragma unroll
      for (int ni = 0; ni < 4; ++ni)
        b[ni] = *(const bf16x8*)&Bs[swz8(ni * 16 + (ln & 15), ks * 4 + (ln >> 4))];
      #pragma unroll
      for (int mi = 0; mi < 2; ++mi)
        #pragma unroll
        for (int ni = 0; ni < 4; ++ni)
          acc[mi][ni] = MFMA(a[mi], b[ni], acc[mi][ni]);
    }
    __syncthreads();
  }
  int bb = m0 >> 10;
  int t_base = m0 & (T_ - 1);
  #pragma unroll
  for (int mi = 0; mi < 2; ++mi) {
    int rloc = wv * 32 + mi * 16 + ((ln >> 4) << 2);
    #pragma unroll
    for (int ni = 0; ni < 4; ++ni) {
      int d = ni * 16 + (ln & 15);
      #pragma unroll
      for (int r = 0; r < 4; ++r) {
        int t = t_base + rloc + r;
        bf16 val = (bf16)acc[mi][ni][r];
        if (w == 0)      Q [(((size_t)bb * H_ + h) * T_ + t) * HD_ + d] = val;
        else if (w == 1) Kk[(((size_t)bb * H_ + h) * T_ + t) * HD_ + d] = val;
        else             Vt[(((size_t)bb * H_ + h) * HD_ + d) * T_ + t] = val;
      }
    }
  }
}

// ---------------- K3: S = (Q K^T) * 1/32 per (b,h); skip fully-masked tiles ----------------
__global__ __launch_bounds__(256) void k_scores(const bf16* __restrict__ Q,
                                                const bf16* __restrict__ Kk,
                                                float* __restrict__ S) {
  int t0 = blockIdx.x * 128, s0 = blockIdx.y * 128, pair = blockIdx.z;
  if (s0 >= t0 + 128) return;   // entire tile above the diagonal -> masked
  __shared__ __align__(16) bf16 As[128 * 64];
  __shared__ __align__(16) bf16 Bs[128 * 64];
  int tid = threadIdx.x, wv = tid >> 6, ln = tid & 63;
  int swsrc = ((ln & 7) ^ (ln >> 3)) * 16;
  const bf16* qb = Q  + (size_t)pair * T_ * HD_;
  const bf16* kb = Kk + (size_t)pair * T_ * HD_;
  #pragma unroll
  for (int i = 0; i < 4; ++i) {
    int r0 = i * 32 + wv * 8, r = r0 + (ln >> 3);
    async_ld16((const char*)(qb + (size_t)(t0 + r) * HD_) + swsrc, &As[r0 * 64]);
    async_ld16((const char*)(kb + (size_t)(s0 + r) * HD_) + swsrc, &Bs[r0 * 64]);
  }
  __syncthreads();
  f32x4 acc[2][8] = {};
  #pragma unroll
  for (int ks = 0; ks < 2; ++ks) {
    bf16x8 a[2], b[8];
    #pragma unroll
    for (int mi = 0; mi < 2; ++mi)
      a[mi] = *(const bf16x8*)&As[swz8(wv * 32 + mi * 16 + (ln & 15), ks * 4 + (ln >> 4))];
    #pragma unroll
    for (int ni = 0; ni < 8; ++ni)
      b[ni] = *(const bf16x8*)&Bs[swz8(ni * 16 + (ln & 15), ks * 4 + (ln >> 4))];
    #pragma unroll
    for (int mi = 0; mi < 2; ++mi)
      #pragma unroll
      for (int ni = 0; ni < 8; ++ni)
        acc[mi][ni] = MFMA(a[mi], b[ni], acc[mi][ni]);
  }
  float* sb = S + (size_t)pair * T_ * T_;
  #pragma unroll
  for (int mi = 0; mi < 2; ++mi) {
    int rloc = t0 + wv * 32 + mi * 16 + ((ln >> 4) << 2);
    #pragma unroll
    for (int ni = 0; ni < 8; ++ni) {
      int col = s0 + ni * 16 + (ln & 15);
      #pragma unroll
      for (int r = 0; r < 4; ++r)
        sb[(size_t)(rloc + r) * T_ + col] = acc[mi][ni][r] * 0.03125f;  // * C^-0.5
    }
  }
}

// ---------------- K4: causal softmax row-wise, S f32 -> P bf16 ----------------
__global__ __launch_bounds__(256) void k_softmax(const float* __restrict__ S,
                                                 bf16* __restrict__ P) {
  int t = blockIdx.x, pair = blockIdx.y;
  const float* srow = S + (size_t)pair * T_ * T_ + (size_t)t * T_;
  bf16* prow = P + (size_t)pair * T_ * T_ + (size_t)t * T_;
  int n = t + 1;
  int tid = threadIdx.x;
  __shared__ float red[256];
  float lm = -1e30f;
  for (int s = tid; s < n; s += 256) lm = fmaxf(lm, srow[s]);
  red[tid] = lm; __syncthreads();
  for (int off = 128; off > 0; off >>= 1) {
    if (tid < off) red[tid] = fmaxf(red[tid], red[tid + off]);
    __syncthreads();
  }
  float m = red[0]; __syncthreads();
  float ls = 0.f;
  for (int s = tid; s < n; s += 256) ls += __expf(srow[s] - m);
  red[tid] = ls; __syncthreads();
  for (int off = 128; off > 0; off >>= 1) {
    if (tid < off) red[tid] += red[tid + off];
    __syncthreads();
  }
  float inv = 1.f / red[0];
  for (int s = tid; s < T_; s += 256) {
    float p = (s < n) ? __expf(srow[s] - m) * inv : 0.f;
    prow[s] = (bf16)p;
  }
}

// ---------------- K5: out = P @ V -> X2[bt][h*64+d] (causal K-loop limit) ----------------
__global__ __launch_bounds__(256) void k_pv(const bf16* __restrict__ P,
                                            const bf16* __restrict__ Vt,
                                            bf16* __restrict__ X2) {
  __shared__ __align__(16) bf16 As[128 * 64];
  __shared__ __align__(16) bf16 Bs[64 * 64];
  int t0 = blockIdx.x * 128, pair = blockIdx.y;
  int bb = pair >> 4, h = pair & 15;
  const bf16* pb = P  + (size_t)pair * T_ * T_;
  const bf16* vb = Vt + (size_t)pair * HD_ * T_;
  int tid = threadIdx.x, wv = tid >> 6, ln = tid & 63;
  int swsrc = ((ln & 7) ^ (ln >> 3)) * 16;
  f32x4 acc[2][4] = {};
  int kmax = (t0 + 128) / 64;       // causal: P[t][s>t]==0
  for (int kt = 0; kt < kmax; ++kt) {
    int k0 = kt * 64;
    #pragma unroll
    for (int i = 0; i < 4; ++i) {
      int r0 = i * 32 + wv * 8, r = r0 + (ln >> 3);
      async_ld16((const char*)(pb + (size_t)(t0 + r) * T_ + k0) + swsrc, &As[r0 * 64]);
    }
    #pragma unroll
    for (int i = 0; i < 2; ++i) {
      int r0 = i * 32 + wv * 8, r = r0 + (ln >> 3);
      async_ld16((const char*)(vb + (size_t)r * T_ + k0) + swsrc, &Bs[r0 * 64]);
    }
    __syncthreads();
    #pragma unroll
    for (int ks = 0; ks < 2; ++ks) {
      bf16x8 a[2], b[4];
      #pragma unroll
      for (int mi = 0; mi < 2; ++mi)
        a[mi] = *(const bf16x8*)&As[swz8(wv * 32 + mi * 16 + (ln & 15), ks * 4 + (ln >> 4))];
      #pragma unroll
      for (int ni = 0; ni < 4; ++ni)
        b[ni] = *(const bf16x8*)&Bs[swz8(ni * 16 + (ln & 15), ks * 4 + (ln >> 4))];
      #pragma unroll
      for (int mi = 0; mi < 2; ++mi)
        #pragma unroll
        for (int ni = 0; ni < 4; ++ni)
          acc[mi][ni] = MFMA(a[mi], b[ni], acc[mi][ni]);
    }
    __syncthreads();
  }
  #pragma unroll
  for (int mi = 0; mi < 2; ++mi) {
    int rloc = wv * 32 + mi * 16 + ((ln >> 4) << 2);
    #pragma unroll
    for (int ni = 0; ni < 4; ++ni) {
      int d = ni * 16 + (ln & 15);
      #pragma unroll
      for (int r = 0; r < 4; ++r) {
        int t = t0 + rloc + r;
        X2[((size_t)bb * T_ + t) * C_ + h * HD_ + d] = (bf16)acc[mi][ni][r];
      }
    }
  }
}

// ---------------- K6: logits = X2 @ W_lm^T + b_lm (M=2048,N=50257,K=1024) ----------------
// Grid swizzle: each XCD owns one n-tile per super-row and sweeps all 16 m-tiles.
__global__ __launch_bounds__(256) void k_lmhead(const bf16* __restrict__ X2,
                                                const float* __restrict__ Wlm,
                                                const float* __restrict__ blm,
                                                float* __restrict__ out) {
  int r = blockIdx.x, s = blockIdx.y;
  int by = s * 8 + (r & 7);
  int bx = r >> 3;
  if (by >= NT_) return;
  int m0 = bx * 128, n0 = by * 128;
  __shared__ __align__(16) bf16 As[128 * 64];
  __shared__ __align__(16) bf16 Bs[128 * 64];
  int tid = threadIdx.x, wv = tid >> 6, ln = tid & 63;
  int swsrc = ((ln & 7) ^ (ln >> 3)) * 16;
  f32x4 acc[2][8] = {};
  for (int kt = 0; kt < C_ / 64; ++kt) {
    int k0 = kt * 64;
    #pragma unroll
    for (int i = 0; i < 4; ++i) {
      int r0 = i * 32 + wv * 8, rr = r0 + (ln >> 3);
      async_ld16((const char*)(X2 + (size_t)(m0 + rr) * C_ + k0) + swsrc, &As[r0 * 64]);
    }
    {
      // stage W_lm fp32 -> bf16: thread covers 32 consecutive floats of one row
      int row = tid >> 1, half = tid & 1;
      int gn = n0 + row; if (gn > V_ - 1) gn = V_ - 1;
      const float4* src = (const float4*)(Wlm + (size_t)gn * C_ + k0 + half * 32);
      union { bf16 e[32]; bf16x8 v8[4]; } tmp;
      #pragma unroll
      for (int j = 0; j < 8; ++j) {
        float4 f = src[j];
        tmp.e[j * 4 + 0] = (bf16)f.x; tmp.e[j * 4 + 1] = (bf16)f.y;
        tmp.e[j * 4 + 2] = (bf16)f.z; tmp.e[j * 4 + 3] = (bf16)f.w;
      }
      #pragma unroll
      for (int j = 0; j < 4; ++j)
        *(bf16x8*)&Bs[swz8(row, half * 4 + j)] = tmp.v8[j];
    }
    __syncthreads();
    #pragma unroll
    for (int ks = 0; ks < 2; ++ks) {
      bf16x8 a[2], b[8];
      #pragma unroll
      for (int mi = 0; mi < 2; ++mi)
        a[mi] = *(const bf16x8*)&As[swz8(wv * 32 + mi * 16 + (ln & 15), ks * 4 + (ln >> 4))];
      #pragma unroll
      for (int ni = 0; ni < 8; ++ni)
        b[ni] = *(const bf16x8*)&Bs[swz8(ni * 16 + (ln & 15), ks * 4 + (ln >> 4))];
      #pragma unroll
      for (int mi = 0; mi < 2; ++mi)
        #pragma unroll
        for (int ni = 0; ni < 8; ++ni)
          acc[mi][ni] = MFMA(a[mi], b[ni], acc[mi][ni]);
    }
    __syncthreads();
  }
  #pragma unroll
  for (int mi = 0; mi < 2; ++mi) {
    int rbase = m0 + wv * 32 + mi * 16 + ((ln >> 4) << 2);
    #pragma unroll
    for (int ni = 0; ni < 8; ++ni) {
      int col = n0 + ni * 16 + (ln & 15);
      if (col < V_) {
        float bias = blm[col];
        #pragma unroll
        for (int rr = 0; rr < 4; ++rr)
          out[(size_t)(rbase + rr) * V_ + col] = acc[mi][ni][rr] + bias;
      }
    }
  }
}

extern "C" void kernel_launch(void* const* d_in, const int* in_sizes, int n_in,
                              void* d_out, int out_size, void* d_ws, size_t ws_size,
                              hipStream_t stream) {
  const int*   idx = (const int*)  d_in[0];
  const float* tok = (const float*)d_in[1];
  const float* pos = (const float*)d_in[2];
  const float* Wq  = (const float*)d_in[3];
  const float* Wk  = (const float*)d_in[4];
  const float* Wv  = (const float*)d_in[5];
  const float* Wlm = (const float*)d_in[6];
  const float* blm = (const float*)d_in[7];
  float* out = (float*)d_out;

  char* ws = (char*)d_ws;
  bf16* X  = (bf16*)(ws + X_OFF);
  bf16* Wt = (bf16*)(ws + WT_OFF);
  bf16* Q  = (bf16*)(ws + Q_OFF);
  bf16* Kk = (bf16*)(ws + K_OFF);
  bf16* Vt = (bf16*)(ws + VT_OFF);
  bf16* X2 = (bf16*)(ws + X2_OFF);

  // d_out doubles as scratch for S (f32, 128 MiB) and P (bf16, 64 MiB);
  // k_lmhead later overwrites every output element.
  float* S = (float*)d_out;
  bf16*  P = (bf16*)((char*)d_out + (size_t)32 * 1024 * 1024 * 4);

  k_prep_wt<<<dim3(16, 48), 256, 0, stream>>>(Wq, Wk, Wv, Wt);
  k_embed  <<<dim3(2048),   256, 0, stream>>>(idx, tok, pos, X);
  k_qkv    <<<dim3(16, 48), 256, 0, stream>>>(X, Wt, Q, Kk, Vt);
  k_scores <<<dim3(8, 8, 32), 256, 0, stream>>>(Q, Kk, S);
  k_softmax<<<dim3(1024, 32), 256, 0, stream>>>(S, P);
  k_pv     <<<dim3(8, 32),  256, 0, stream>>>(P, Vt, X2);
  k_lmhead <<<dim3(128, 50), 256, 0, stream>>>(X2, Wlm, blm, out);
}